// Round 6
// baseline (451.150 us; speedup 1.0000x reference)
//
#include <hip/hip_runtime.h>
#include <stdint.h>

#define NN 100000      // nodes
#define EE 500000      // edges
#define HIDD 256
#define LN_EPS 1e-5f

typedef _Float16 half8 __attribute__((ext_vector_type(8)));  // 8 fp16 (4 VGPRs)
typedef _Float16 half4 __attribute__((ext_vector_type(4)));
typedef __fp16 fp16x2 __attribute__((ext_vector_type(2)));   // builtin return type
typedef float f32x4 __attribute__((ext_vector_type(4)));
typedef float f32x2 __attribute__((ext_vector_type(2)));     // v_pk_*_f32 carrier
typedef float f32x16 __attribute__((ext_vector_type(16)));   // 32x32 MFMA acc

// lgkm-only barrier: makes LDS writes visible WITHOUT draining vmcnt (global loads
// stay in flight across it).
#define LBAR() asm volatile("s_waitcnt lgkmcnt(0)\n\ts_barrier" ::: "memory")

__device__ __forceinline__ unsigned short f2h(float f) {
  _Float16 h = (_Float16)f;                 // v_cvt_f16_f32, RNE
  union { _Float16 hh; unsigned short us; } u; u.hh = h;
  return u.us;
}

__device__ __forceinline__ unsigned pkrtz(float a, float b) {
  union { fp16x2 h; unsigned u; } c;
  c.h = __builtin_amdgcn_cvt_pkrtz(a, b);   // 1 instr: 2×f32 -> packed fp16
  return c.u;
}

__device__ __forceinline__ float fast_silu(float y) {
  float e = __expf(-y);
  return y * __builtin_amdgcn_rcpf(1.f + e);     // rcp instead of full div
}

__device__ __forceinline__ half8 ldg8(const unsigned short* p) {
  return *(const half8*)p;                  // global_load_dwordx4
}

// fp32 row-piece -> packed fp16 int4 (use_hb=0 fallback)
__device__ __forceinline__ int4 cvt_row(const float* s) {
  float4 a0 = *(const float4*)s, a1 = *(const float4*)(s + 4);
  uint4 ua;
  ua.x = pkrtz(a0.x, a0.y); ua.y = pkrtz(a0.z, a0.w);
  ua.z = pkrtz(a1.x, a1.y); ua.w = pkrtz(a1.z, a1.w);
  return *(int4*)&ua;
}

// ---- merged prep: weight swizzle (blocks 0..711) + h f32->fp16 (blocks 712..13211) ----
// Round-6: W1/W2 stored for the 32x32x16 A-fragment: lane l reads
// A[m = l&31][k = kstep*16 + (l>>5)*8 + j], j=0..7 contiguous.
// Layout: w1sw[kstep*4096 + m*16 + hi*8 + j]  (36 ksteps x 256 m x 16)
//         w2sw[kstep*2048 + m*16 + hi*8 + j]  (16 ksteps x 128 m x 16)
__global__ __launch_bounds__(256) void prep_kern(const float* __restrict__ h,
                                                 const float* __restrict__ W1,
                                                 const float* __restrict__ W2,
                                                 const float* __restrict__ W3,
                                                 unsigned short* __restrict__ hb,
                                                 unsigned short* __restrict__ w1sw,
                                                 unsigned short* __restrict__ w2sw,
                                                 unsigned short* __restrict__ w3sw) {
  int b = blockIdx.x;
  if (b < 712) {
    int t = b * 256 + threadIdx.x;
    if (t < 147456) {
      int kstep = t >> 12;            // 0..35
      int rem = t & 4095;
      int m = rem >> 4;               // 0..255
      int hi = (rem >> 3) & 1;
      int j = t & 7;
      int k = kstep * 16 + hi * 8 + j;
      w1sw[t] = f2h((k < 551) ? W1[k * 256 + m] : 0.f);
    } else if (t < 147456 + 32768) {
      int t2 = t - 147456;
      int kstep = t2 >> 11;           // 0..15
      int rem = t2 & 2047;
      int m = rem >> 4;               // 0..127
      int hi = (rem >> 3) & 1;
      int j = t2 & 7;
      int k = kstep * 16 + hi * 8 + j;
      w2sw[t2] = f2h(W2[k * 128 + m]);
    } else if (t < 147456 + 32768 + 2048) {
      int t3 = t - 180224;
      int kq = t3 >> 7, o = (t3 >> 3) & 15, j = t3 & 7;
      int k = (kq << 3) + j;
      w3sw[t3] = f2h((o < 5) ? W3[k * 5 + o] : 0.f);   // GEMM3 stays 16x16x32
    }
  } else {
    int i = ((b - 712) * 256 + threadIdx.x) * 8;   // N*HID = 25.6M = 12500*256*8
    float4 v0 = *(const float4*)(h + i);
    float4 v1 = *(const float4*)(h + i + 4);
    uint4 u;
    u.x = pkrtz(v0.x, v0.y); u.y = pkrtz(v0.z, v0.w);
    u.z = pkrtz(v1.x, v1.y); u.w = pkrtz(v1.z, v1.w);
    *(uint4*)(hb + i) = u;
  }
}

// ---- fused main kernel: 64 edges/block, 256 threads (4 waves), 3 blocks/CU ----
// Cross-round invariants (r0-r5): wall ~250us vs MFMA-pipe floor ~88us at the
// 16x16x32 rate; phase topology (r2/r3/r5) and staging depth don't move it.
// Round-6: GEMM1/GEMM2 on 32x32x16 MFMA (ubench 2382 vs 2075 TF: floor 88->76us)
// and HALF the MFMA instruction count (issue-slot relief). C/D layout (verified
// m74/m101): col = lane&31, row = (reg&3) + 8*(reg>>2) + 4*(lane>>5).
// A-frag: A[m=lane&31][k=(lane>>5)*8+j]; B-frag: B[k=(lane>>5)*8+j][n=lane&31].
// Per wave: 2 m-tiles (64 ch) x 2 n-tiles (64 edges), acc 2x2 x f32x16 (64 regs,
// same as before). LN reduce: 32 ch/lane -> ONE shfl_xor(32) (was xor16+xor32).
// Staging / fat phases / output identical to r5. GEMM3 stays 16x16x32.
struct __align__(16) SMem {
  short r1[16384];    // 32768B: GEMM1 dbuf (2 x 2chunks x 4096el) -> z1T [64][256]swz -> z2T [64][128]swz
  short feats[4096];  // 8192B : built features chunk (K rows 512..575), swz
  float red[512];     // 2048B : LN partials (S [0..255], Q [256..511]) -> out staging (320f)
  _Float16 b1h[256], g1h[256], be1h[256];   // 1536B
  _Float16 b2h[128], g2h[128], be2h[128];   // 768B
  float muv[16];      // 64B
  float b3v[8];       // 32B
  int spI[64], exI[64];                     // 512B
};  // ~45.8 KB -> 3 blocks/CU (137 KB < 160 KB)

__global__ __launch_bounds__(256, 3)
void edge_head_main(const float* __restrict__ h, const float* __restrict__ x,
                    const int* __restrict__ spawn, const int* __restrict__ exist,
                    const float* __restrict__ insx, const int* __restrict__ insa,
                    const int* __restrict__ insc,
                    const float* __restrict__ b1, const float* __restrict__ g1,
                    const float* __restrict__ be1,
                    const float* __restrict__ b2, const float* __restrict__ g2,
                    const float* __restrict__ be2,
                    const float* __restrict__ b3, const float* __restrict__ mu,
                    const float* __restrict__ gammaP,
                    const unsigned short* __restrict__ w1sw,
                    const unsigned short* __restrict__ w2sw,
                    const unsigned short* __restrict__ w3swg,
                    const unsigned short* __restrict__ hb, int use_hb,
                    float* __restrict__ out) {
  __shared__ SMem sm;
  const int t = threadIdx.x;
  const int base = blockIdx.x * 64;
  const int lane = t & 63;
  const int wv = t >> 6;
  const int cl = lane & 15;        // GEMM3 / staging helpers
  const int q = lane >> 4;
  const int l31 = lane & 31;       // 32x32 lane coords
  const int hi = lane >> 5;
  const int sxr = (l31 & 7) << 3;  // B-frag swizzle term (row&7 == l31&7 for both n-tiles)

  // ---- const staging ----
  sm.b1h[t] = (_Float16)b1[t]; sm.g1h[t] = (_Float16)g1[t]; sm.be1h[t] = (_Float16)be1[t];
  if (t < 128) { sm.b2h[t] = (_Float16)b2[t]; sm.g2h[t] = (_Float16)g2[t]; sm.be2h[t] = (_Float16)be2[t]; }
  if (t < 16) sm.muv[t] = mu[t];
  if (t < 8) sm.b3v[t] = (t < 5) ? b3[t] : 0.f;
  if (t < 64) {
    int e = base + t; int ec = e < EE ? e : EE - 1;
    sm.spI[t] = spawn[ec]; sm.exI[t] = exist[ec];
  }
  const float gma = gammaP[0];

  LBAR();   // B0: indices + consts visible

  // ---- distance / one-hot prep for the features chunk (t<64, wave 0) ----
  float dreg = 0.f;
  int k1 = 16, k2 = 32;
  if (t < 64) {
    int e = base + t; int ec = e < EE ? e : EE - 1;
    float ix0 = insx[ec * 3], ix1 = insx[ec * 3 + 1], ix2 = insx[ec * 3 + 2];
    int nd = sm.exI[t];
    float dx = ix0 - x[nd * 3], dy = ix1 - x[nd * 3 + 1], dz = ix2 - x[nd * 3 + 2];
    dreg = fmaxf(sqrtf(dx * dx + dy * dy + dz * dz), 1e-6f);
    k1 = 16 + insa[ec]; k2 = 32 + insc[ec];
  }

  // gather slots: thread fills feats rows row0 (16B piece p0) and row1 (=row0+32)
  const int row0 = t >> 3, p0 = t & 7;
  const int row1 = row0 + 32;
  const int sw0 = ((p0 ^ (row0 & 7)) << 3);
  const int sw1 = ((p0 ^ (row1 & 7)) << 3);

  // hoisted gather base pointers
  const size_t oSp0 = (size_t)sm.spI[row0] * HIDD + p0 * 8;
  const size_t oSp1 = (size_t)sm.spI[row1] * HIDD + p0 * 8;
  const size_t oEx0 = (size_t)sm.exI[row0] * HIDD + p0 * 8;
  const size_t oEx1 = (size_t)sm.exI[row1] * HIDD + p0 * 8;
  const char* bSp0 = use_hb ? (const char*)(hb + oSp0) : (const char*)(h + oSp0);
  const char* bSp1 = use_hb ? (const char*)(hb + oSp1) : (const char*)(h + oSp1);
  const char* bEx0 = use_hb ? (const char*)(hb + oEx0) : (const char*)(h + oEx0);
  const char* bEx1 = use_hb ? (const char*)(hb + oEx1) : (const char*)(h + oEx1);

  // phase ph (0..3): gather chunks 2ph (colb (ph&1)*128) and 2ph+1 (+64);
  // ph<2 = spawn half, ph>=2 = exist half.
  int4 pS0, pS1, pS2, pS3;
#define GLOAD2(ph) do {                                                 \
    const char* b0_ = ((ph) < 2) ? bSp0 : bEx0;                         \
    const char* b1_ = ((ph) < 2) ? bSp1 : bEx1;                         \
    const int ce_ = ((ph) & 1) * 128;                                   \
    if (use_hb) {                                                       \
      pS0 = *(const int4*)(b0_ + ce_ * 2);                              \
      pS1 = *(const int4*)(b1_ + ce_ * 2);                              \
      pS2 = *(const int4*)(b0_ + (ce_ + 64) * 2);                       \
      pS3 = *(const int4*)(b1_ + (ce_ + 64) * 2);                       \
    } else {                                                            \
      pS0 = cvt_row((const float*)(b0_ + ce_ * 4));                     \
      pS1 = cvt_row((const float*)(b1_ + ce_ * 4));                     \
      pS2 = cvt_row((const float*)(b0_ + (ce_ + 64) * 4));              \
      pS3 = cvt_row((const float*)(b1_ + (ce_ + 64) * 4));              \
    }                                                                   \
  } while (0)

  // pre-loop: phase 0 loads -> stage buf0; phase 1 loads in flight
  GLOAD2(0);
  *(int4*)&sm.r1[row0 * 64 + sw0] = pS0;
  *(int4*)&sm.r1[row1 * 64 + sw1] = pS1;
  *(int4*)&sm.r1[4096 + row0 * 64 + sw0] = pS2;
  *(int4*)&sm.r1[4096 + row1 * 64 + sw1] = pS3;
  GLOAD2(1);

  // W1 A-frag base: lane reads w1sw[kstep*4096 + m*16 + hi*8 ...], m = wv*64 + mt*32 + l31
  const unsigned short* w1p = w1sw + (wv * 64 + l31) * 16 + hi * 8;

  // build features chunk -> sm.feats (wave 0)
  if (t < 64) {
    short* rp = &sm.feats[t * 64];
    const int sw = t & 7;
    float rb[16];
#pragma unroll
    for (int k = 0; k < 16; ++k) { float dd = dreg - sm.muv[k]; rb[k] = __expf(-gma * dd * dd); }
    uint4 ua, ub;
    ua.x = pkrtz(rb[0], rb[1]);  ua.y = pkrtz(rb[2], rb[3]);
    ua.z = pkrtz(rb[4], rb[5]);  ua.w = pkrtz(rb[6], rb[7]);
    ub.x = pkrtz(rb[8], rb[9]);  ub.y = pkrtz(rb[10], rb[11]);
    ub.z = pkrtz(rb[12], rb[13]); ub.w = pkrtz(rb[14], rb[15]);
    *(int4*)&rp[(0 ^ sw) * 8] = *(int4*)&ua;
    *(int4*)&rp[(1 ^ sw) * 8] = *(int4*)&ub;
    const int4 z4 = {0, 0, 0, 0};
#pragma unroll
    for (int g = 2; g < 8; ++g) *(int4*)&rp[(g ^ sw) * 8] = z4;
    rp[((k1 >> 3) ^ sw) * 8 + (k1 & 7)] = (short)0x3C00;   // fp16 1.0
    rp[((k2 >> 3) ^ sw) * 8 + (k2 & 7)] = (short)0x3C00;
  }

  LBAR();   // buf0 + feats visible

  // ---- GEMM1: z1^T[256][64] = W1^T * feats^T, K=576, 32x32x16 MFMA ----
  f32x16 acc[2][2];
#pragma unroll
  for (int mt = 0; mt < 2; ++mt)
#pragma unroll
    for (int nt = 0; nt < 2; ++nt)
#pragma unroll
      for (int r = 0; r < 16; ++r) acc[mt][nt][r] = 0.f;

#pragma unroll
  for (int p = 0; p < 4; ++p) {
    // stage phase p+1's chunks; reload pS for phase p+2
    if (p < 3) {
      const int nb = ((p + 1) & 1) * 8192;
      *(int4*)&sm.r1[nb + row0 * 64 + sw0] = pS0;   // vmcnt wait auto (data dep)
      *(int4*)&sm.r1[nb + row1 * 64 + sw1] = pS1;
      *(int4*)&sm.r1[nb + 4096 + row0 * 64 + sw0] = pS2;
      *(int4*)&sm.r1[nb + 4096 + row1 * 64 + sw1] = pS3;
      if (p < 2) GLOAD2(p + 2);
    }
    // MFMA: 2 chunks x 4 ksteps x (2mt x 2nt) = 32 MFMAs of 32x32x16
    const int cb = (p & 1) * 8192;
#pragma unroll
    for (int ch = 0; ch < 2; ++ch) {
      const int kc = 2 * p + ch;           // phys chunk 0..7
#pragma unroll
      for (int sc = 0; sc < 4; ++sc) {     // kstep within chunk
        const int koff = sc * 16 + hi * 8;
        half8 bf0 = *(const half8*)&sm.r1[cb + ch * 4096 + l31 * 64 + (koff ^ sxr)];
        half8 bf1 = *(const half8*)&sm.r1[cb + ch * 4096 + (32 + l31) * 64 + (koff ^ sxr)];
        half8 fX0 = ldg8(w1p + (kc * 4 + sc) * 4096);
        half8 fX1 = ldg8(w1p + (kc * 4 + sc) * 4096 + 512);
        acc[0][0] = __builtin_amdgcn_mfma_f32_32x32x16_f16(fX0, bf0, acc[0][0], 0, 0, 0);
        acc[0][1] = __builtin_amdgcn_mfma_f32_32x32x16_f16(fX0, bf1, acc[0][1], 0, 0, 0);
        acc[1][0] = __builtin_amdgcn_mfma_f32_32x32x16_f16(fX1, bf0, acc[1][0], 0, 0, 0);
        acc[1][1] = __builtin_amdgcn_mfma_f32_32x32x16_f16(fX1, bf1, acc[1][1], 0, 0, 0);
      }
    }
    if (p < 3) LBAR();   // phase p+1 stage visible; all waves done with buf[p&1]
  }
#undef GLOAD2

  // features chunk (phys chunk 8 = ksteps 32..35) from sm.feats
#pragma unroll
  for (int sc = 0; sc < 4; ++sc) {
    const int koff = sc * 16 + hi * 8;
    half8 bf0 = *(const half8*)&sm.feats[l31 * 64 + (koff ^ sxr)];
    half8 bf1 = *(const half8*)&sm.feats[(32 + l31) * 64 + (koff ^ sxr)];
    half8 fX0 = ldg8(w1p + (32 + sc) * 4096);
    half8 fX1 = ldg8(w1p + (32 + sc) * 4096 + 512);
    acc[0][0] = __builtin_amdgcn_mfma_f32_32x32x16_f16(fX0, bf0, acc[0][0], 0, 0, 0);
    acc[0][1] = __builtin_amdgcn_mfma_f32_32x32x16_f16(fX0, bf1, acc[0][1], 0, 0, 0);
    acc[1][0] = __builtin_amdgcn_mfma_f32_32x32x16_f16(fX1, bf0, acc[1][0], 0, 0, 0);
    acc[1][1] = __builtin_amdgcn_mfma_f32_32x32x16_f16(fX1, bf1, acc[1][1], 0, 0, 0);
  }

  // ---- +b1 (fused), LN over 256 channels, SiLU, pack to z1T ----
  // lane holds channels wv*64 + mt*32 + (reg&3)+8*(reg>>2)+4*hi; edge = nt*32+l31.
  float S1[2], Q1[2];
  {
    f32x2 s2[2] = {{0.f, 0.f}, {0.f, 0.f}};
    f32x2 q2[2] = {{0.f, 0.f}, {0.f, 0.f}};
#pragma unroll
    for (int mt = 0; mt < 2; ++mt)
#pragma unroll
      for (int g = 0; g < 4; ++g) {
        half4 b4 = *(const half4*)&sm.b1h[wv * 64 + mt * 32 + 8 * g + 4 * hi];
        f32x2 bb0 = (f32x2){(float)b4[0], (float)b4[1]};
        f32x2 bb1 = (f32x2){(float)b4[2], (float)b4[3]};
#pragma unroll
        for (int nt = 0; nt < 2; ++nt) {
          f32x2 v0 = (f32x2){acc[mt][nt][4 * g + 0], acc[mt][nt][4 * g + 1]} + bb0;
          f32x2 v1 = (f32x2){acc[mt][nt][4 * g + 2], acc[mt][nt][4 * g + 3]} + bb1;
          acc[mt][nt][4 * g + 0] = v0[0]; acc[mt][nt][4 * g + 1] = v0[1];
          acc[mt][nt][4 * g + 2] = v1[0]; acc[mt][nt][4 * g + 3] = v1[1];
          s2[nt] += v0 + v1;
          q2[nt] += v0 * v0;
          q2[nt] += v1 * v1;
        }
      }
#pragma unroll
    for (int nt = 0; nt < 2; ++nt) {
      float S = s2[nt][0] + s2[nt][1], Q = q2[nt][0] + q2[nt][1];
      S += __shfl_xor(S, 32);          // combine hi halves: full 64-ch wave partial
      Q += __shfl_xor(Q, 32);
      S1[nt] = S; Q1[nt] = Q;
    }
  }
  if (hi == 0) {
#pragma unroll
    for (int nt = 0; nt < 2; ++nt) {
      sm.red[wv * 64 + nt * 32 + l31] = S1[nt];
      sm.red[256 + wv * 64 + nt * 32 + l31] = Q1[nt];
    }
  }
  LBAR();   // red1 visible; all waves past GEMM1 -> r1 reusable as z1T
  f32x2 rs1[2], mr1[2];
#pragma unroll
  for (int nt = 0; nt < 2; ++nt) {
    int e = nt * 32 + l31;
    float S = sm.red[e] + sm.red[64 + e] + sm.red[128 + e] + sm.red[192 + e];
    float Q = sm.red[256 + e] + sm.red[320 + e] + sm.red[384 + e] + sm.red[448 + e];
    float mn = S * (1.f / 256.f);
    float rs = rsqrtf(Q * (1.f / 256.f) - mn * mn + LN_EPS);
    rs1[nt] = (f32x2){rs, rs};
    mr1[nt] = (f32x2){-mn * rs, -mn * rs};
  }
#pragma unroll
  for (int mt = 0; mt < 2; ++mt)
#pragma unroll
    for (int g = 0; g < 4; ++g) {
      const int cb4 = wv * 64 + mt * 32 + 8 * g + 4 * hi;   // channel of pair base
      half4 g4 = *(const half4*)&sm.g1h[cb4];
      half4 e4 = *(const half4*)&sm.be1h[cb4];
      f32x2 gg0 = (f32x2){(float)g4[0], (float)g4[1]}, gg1 = (f32x2){(float)g4[2], (float)g4[3]};
      f32x2 ee0 = (f32x2){(float)e4[0], (float)e4[1]}, ee1 = (f32x2){(float)e4[2], (float)e4[3]};
#pragma unroll
      for (int nt = 0; nt < 2; ++nt) {
        f32x2 v0 = (f32x2){acc[mt][nt][4 * g + 0], acc[mt][nt][4 * g + 1]};
        f32x2 v1 = (f32x2){acc[mt][nt][4 * g + 2], acc[mt][nt][4 * g + 3]};
        f32x2 t0 = v0 * rs1[nt] + mr1[nt];
        f32x2 t1 = v1 * rs1[nt] + mr1[nt];
        f32x2 y0 = t0 * gg0 + ee0;
        f32x2 y1 = t1 * gg1 + ee1;
        float s0 = fast_silu(y0[0]), s1 = fast_silu(y0[1]);
        float s2v = fast_silu(y1[0]), s3 = fast_silu(y1[1]);
        uint2 w; w.x = pkrtz(s0, s1); w.y = pkrtz(s2v, s3);
        int m = nt * 32 + l31;
        *(uint2*)&sm.r1[m * 256 + (cb4 ^ ((m & 7) << 3))] = w;   // z1T swz
      }
    }
  LBAR();   // z1T visible

  // W3 fragments (16x16 layout): issue early, consumed at GEMM3
  half8 af3[4];
#pragma unroll
  for (int ks = 0; ks < 4; ++ks)
    af3[ks] = ldg8(w3swg + (ks * 4 + q) * 128 + cl * 8);

  // ---- GEMM2: z2^T[128][64] = W2^T * z1^T, 32x32x16, barrier-free ----
  // wave owns channels wv*32..+31 (1 m-tile); 2 n-tiles; K=256 = 16 ksteps.
  const unsigned short* w2p = w2sw + (wv * 32 + l31) * 16 + hi * 8;
  f32x16 acc2[2];
#pragma unroll
  for (int nt = 0; nt < 2; ++nt)
#pragma unroll
    for (int r = 0; r < 16; ++r) acc2[nt][r] = 0.f;
#pragma unroll
  for (int ks = 0; ks < 16; ++ks) {
    const int koff = ks * 16 + hi * 8;
    half8 a0 = ldg8(w2p + ks * 2048);
    half8 bf0 = *(const half8*)&sm.r1[l31 * 256 + (koff ^ sxr)];
    half8 bf1 = *(const half8*)&sm.r1[(32 + l31) * 256 + (koff ^ sxr)];
    acc2[0] = __builtin_amdgcn_mfma_f32_32x32x16_f16(a0, bf0, acc2[0], 0, 0, 0);
    acc2[1] = __builtin_amdgcn_mfma_f32_32x32x16_f16(a0, bf1, acc2[1], 0, 0, 0);
  }

  // ---- +b2 (fused), LN over 128, SiLU, pack z2T (overlays z1T head in r1) ----
  float S2a[2], Q2a[2];
  {
    f32x2 s2[2] = {{0.f, 0.f}, {0.f, 0.f}};
    f32x2 q2[2] = {{0.f, 0.f}, {0.f, 0.f}};
#pragma unroll
    for (int g = 0; g < 4; ++g) {
      half4 b4 = *(const half4*)&sm.b2h[wv * 32 + 8 * g + 4 * hi];
      f32x2 bb0 = (f32x2){(float)b4[0], (float)b4[1]};
      f32x2 bb1 = (f32x2){(float)b4[2], (float)b4[3]};
#pragma unroll
      for (int nt = 0; nt < 2; ++nt) {
        f32x2 v0 = (f32x2){acc2[nt][4 * g + 0], acc2[nt][4 * g + 1]} + bb0;
        f32x2 v1 = (f32x2){acc2[nt][4 * g + 2], acc2[nt][4 * g + 3]} + bb1;
        acc2[nt][4 * g + 0] = v0[0]; acc2[nt][4 * g + 1] = v0[1];
        acc2[nt][4 * g + 2] = v1[0]; acc2[nt][4 * g + 3] = v1[1];
        s2[nt] += v0 + v1;
        q2[nt] += v0 * v0;
        q2[nt] += v1 * v1;
      }
    }
#pragma unroll
    for (int nt = 0; nt < 2; ++nt) {
      float S = s2[nt][0] + s2[nt][1], Q = q2[nt][0] + q2[nt][1];
      S += __shfl_xor(S, 32);
      Q += __shfl_xor(Q, 32);
      S2a[nt] = S; Q2a[nt] = Q;
    }
  }
  if (hi == 0) {
#pragma unroll
    for (int nt = 0; nt < 2; ++nt) {
      sm.red[wv * 64 + nt * 32 + l31] = S2a[nt];
      sm.red[256 + wv * 64 + nt * 32 + l31] = Q2a[nt];
    }
  }
  LBAR();   // red2 visible; z1T dead -> z2T region safe
  f32x2 rs2[2], mr2[2];
#pragma unroll
  for (int nt = 0; nt < 2; ++nt) {
    int e = nt * 32 + l31;
    float S = sm.red[e] + sm.red[64 + e] + sm.red[128 + e] + sm.red[192 + e];
    float Q = sm.red[256 + e] + sm.red[320 + e] + sm.red[384 + e] + sm.red[448 + e];
    float mn = S * (1.f / 128.f);
    float rs = rsqrtf(Q * (1.f / 128.f) - mn * mn + LN_EPS);
    rs2[nt] = (f32x2){rs, rs};
    mr2[nt] = (f32x2){-mn * rs, -mn * rs};
  }
#pragma unroll
  for (int g = 0; g < 4; ++g) {
    const int cb4 = wv * 32 + 8 * g + 4 * hi;
    half4 g4 = *(const half4*)&sm.g2h[cb4];
    half4 e4 = *(const half4*)&sm.be2h[cb4];
    f32x2 gg0 = (f32x2){(float)g4[0], (float)g4[1]}, gg1 = (f32x2){(float)g4[2], (float)g4[3]};
    f32x2 ee0 = (f32x2){(float)e4[0], (float)e4[1]}, ee1 = (f32x2){(float)e4[2], (float)e4[3]};
#pragma unroll
    for (int nt = 0; nt < 2; ++nt) {
      f32x2 v0 = (f32x2){acc2[nt][4 * g + 0], acc2[nt][4 * g + 1]};
      f32x2 v1 = (f32x2){acc2[nt][4 * g + 2], acc2[nt][4 * g + 3]};
      f32x2 t0 = v0 * rs2[nt] + mr2[nt];
      f32x2 t1 = v1 * rs2[nt] + mr2[nt];
      f32x2 y0 = t0 * gg0 + ee0;
      f32x2 y1 = t1 * gg1 + ee1;
      float s0 = fast_silu(y0[0]), s1 = fast_silu(y0[1]);
      float s2v = fast_silu(y1[0]), s3 = fast_silu(y1[1]);
      uint2 w; w.x = pkrtz(s0, s1); w.y = pkrtz(s2v, s3);
      int m = nt * 32 + l31;
      *(uint2*)&sm.r1[m * 128 + (cb4 ^ ((m & 7) << 3))] = w;   // z2T swz (r1 head)
    }
  }
  LBAR();   // z2T visible

  // ---- GEMM3: out^T[16][64] = W3^T * z2^T (o padded 5->16), 16x16x32 ----
  f32x4 a3 = (f32x4){0.f, 0.f, 0.f, 0.f};
  const int m3 = wv * 16 + cl;
  const int sx3 = (m3 & 7) << 3;
#pragma unroll
  for (int ks = 0; ks < 4; ++ks) {
    half8 bfv = *(const half8*)&sm.r1[m3 * 128 + ((ks * 32 + q * 8) ^ sx3)];
    a3 = __builtin_amdgcn_mfma_f32_16x16x32_f16(af3[ks], bfv, a3, 0, 0, 0);
  }
  // stage the 64x5 output tile in LDS (red[] dead) and write coalesced float4s
#pragma unroll
  for (int r = 0; r < 4; ++r) {
    int o = q * 4 + r;
    if (o < 5) sm.red[m3 * 5 + o] = a3[r] + sm.b3v[o];
  }
  LBAR();   // out tile visible
  if (t < 80) {
    size_t g = (size_t)base * 5 + (size_t)t * 4;
    if (g + 4 <= (size_t)EE * 5) {
      *(float4*)(out + g) = *(const float4*)&sm.red[t * 4];
    } else {
#pragma unroll
      for (int u = 0; u < 4; ++u)
        if (g + u < (size_t)EE * 5) out[g + u] = sm.red[t * 4 + u];
    }
  }
}

extern "C" void kernel_launch(void* const* d_in, const int* in_sizes, int n_in,
                              void* d_out, int out_size, void* d_ws, size_t ws_size,
                              hipStream_t stream) {
  const float* h    = (const float*)d_in[0];
  const float* x    = (const float*)d_in[1];
  const int* spawn  = (const int*)d_in[2];
  const int* exist  = (const int*)d_in[3];
  const float* insx = (const float*)d_in[4];
  const int* insa   = (const int*)d_in[5];
  const int* insc   = (const int*)d_in[6];
  const float* W1   = (const float*)d_in[7];
  const float* b1   = (const float*)d_in[8];
  const float* g1   = (const float*)d_in[9];
  const float* be1  = (const float*)d_in[10];
  const float* W2   = (const float*)d_in[11];
  const float* b2   = (const float*)d_in[12];
  const float* g2   = (const float*)d_in[13];
  const float* be2  = (const float*)d_in[14];
  const float* W3   = (const float*)d_in[15];
  const float* b3   = (const float*)d_in[16];
  const float* mu   = (const float*)d_in[17];
  const float* gma  = (const float*)d_in[18];

  unsigned short* w1sw = (unsigned short*)d_ws;          // 147456 el
  unsigned short* w2sw = w1sw + 147456;                  // 32768 el
  unsigned short* w3sw = w2sw + 32768;                   // 2048 el
  unsigned short* hb   = w3sw + 2048;                    // N*HID el (optional)
  const size_t need_hb = 364544ull + (size_t)NN * HIDD * 2ull;
  int use_hb = (ws_size >= need_hb) ? 1 : 0;

  prep_kern<<<use_hb ? 13212 : 712, 256, 0, stream>>>(h, W1, W2, W3, hb, w1sw, w2sw, w3sw);
  edge_head_main<<<7813, 256, 0, stream>>>(h, x, spawn, exist, insx, insa, insc,
                                           b1, g1, be1, b2, g2, be2, b3, mu, gma,
                                           w1sw, w2sw, w3sw, hb, use_hb,
                                           (float*)d_out);
}

// Round 7
// 427.375 us; speedup vs baseline: 1.0556x; 1.0556x over previous
//
#include <hip/hip_runtime.h>
#include <stdint.h>

#define NN 100000      // nodes
#define EE 500000      // edges
#define HIDD 256
#define LN_EPS 1e-5f

typedef _Float16 half8 __attribute__((ext_vector_type(8)));  // 8 fp16 (4 VGPRs)
typedef _Float16 half4 __attribute__((ext_vector_type(4)));
typedef __fp16 fp16x2 __attribute__((ext_vector_type(2)));   // builtin return type
typedef float f32x4 __attribute__((ext_vector_type(4)));
typedef float f32x2 __attribute__((ext_vector_type(2)));     // v_pk_*_f32 carrier

// lgkm-only barrier: LDS writes visible WITHOUT draining vmcnt (global loads fly on).
#define LBAR() asm volatile("s_waitcnt lgkmcnt(0)\n\ts_barrier" ::: "memory")

__device__ __forceinline__ unsigned short f2h(float f) {
  _Float16 h = (_Float16)f;
  union { _Float16 hh; unsigned short us; } u; u.hh = h;
  return u.us;
}

__device__ __forceinline__ unsigned pkrtz(float a, float b) {
  union { fp16x2 h; unsigned u; } c;
  c.h = __builtin_amdgcn_cvt_pkrtz(a, b);
  return c.u;
}

__device__ __forceinline__ float fast_silu(float y) {
  float e = __expf(-y);
  return y * __builtin_amdgcn_rcpf(1.f + e);
}

__device__ __forceinline__ half8 ldg8(const unsigned short* p) {
  return *(const half8*)p;                  // global_load_dwordx4
}

// 8 consecutive f32 -> packed fp16 int4
__device__ __forceinline__ int4 cvt_row(const float* s) {
  float4 a0 = *(const float4*)s, a1 = *(const float4*)(s + 4);
  uint4 ua;
  ua.x = pkrtz(a0.x, a0.y); ua.y = pkrtz(a0.z, a0.w);
  ua.z = pkrtz(a1.x, a1.y); ua.w = pkrtz(a1.z, a1.w);
  return *(int4*)&ua;
}

// =======================  NEW (P-precompute) PATH  =======================
// z1[e] = P1[spawn[e]] + P2[exist[e]] + W1f^T feat[e]
//   P1 = h @ W1[0:256], P2 = h @ W1[256:512]  (per-NODE: 26 GFLOP unique vs the
//   131 GFLOP the per-EDGE GEMM1 was recomputing at ~5x node multiplicity).
// P stored fp16 [node][512] (P1 = cols 0..255, P2 = 256..511) — same rounding
// class as the old fp16-h gather path.

// ---- prep_w: weight swizzles for the P path (712 blocks x 256 = 182272) ----
// wc  [131072]: Wcat A-frags for pgemm: [kq(0..31)][mm(0..511)][j(0..7)],
//               k = kq*8+j; Wcat[k][mm] = mm<256 ? W1[k][mm] : W1[256+k][mm-256]
// w1f [16384] : feat-chunk A-frags (old chunk-8 layout): k = 512 + kq*8 + j
// w2sw[32768] : GEMM2 16x16 A-frags (unchanged layout)
// w3sw[2048]  : GEMM3 A-frags (unchanged)
__global__ __launch_bounds__(256) void prep_w(const float* __restrict__ W1,
                                              const float* __restrict__ W2,
                                              const float* __restrict__ W3,
                                              unsigned short* __restrict__ wc,
                                              unsigned short* __restrict__ w1f,
                                              unsigned short* __restrict__ w2sw,
                                              unsigned short* __restrict__ w3sw) {
  int t = blockIdx.x * 256 + threadIdx.x;
  if (t < 131072) {
    int kq = t >> 12, mm = (t >> 3) & 511, j = t & 7;
    int k = kq * 8 + j;                       // 0..255
    int row = k + ((mm < 256) ? 0 : 256);
    wc[t] = f2h(W1[row * 256 + (mm & 255)]);
  } else if (t < 147456) {
    int t2 = t - 131072;
    int kq = t2 >> 11, m = (t2 >> 3) & 255, j = t2 & 7;
    int k = 512 + kq * 8 + j;
    w1f[t2] = f2h((k < 551) ? W1[k * 256 + m] : 0.f);
  } else if (t < 180224) {
    int t2 = t - 147456;
    int chunk = t2 >> 13, rem = t2 & 8191;
    int kq = rem >> 10, n = (rem >> 3) & 127, j = rem & 7;
    int k = (chunk << 6) + (kq << 3) + j;
    w2sw[t2] = f2h(W2[k * 128 + n]);
  } else if (t < 182272) {
    int t3 = t - 180224;
    int kq = t3 >> 7, o = (t3 >> 3) & 15, j = t3 & 7;
    int k = (kq << 3) + j;
    w3sw[t3] = f2h((o < 5) ? W3[k * 5 + o] : 0.f);
  }
}

// ---- pgemm: P[100000][512] fp16 = h[100000][256] @ Wcat[256][512] ----
// 3126 blocks: tile = 64 nodes x 256 cols (col-half ch). 256 threads / 4 waves,
// wave owns 64 output cols. Dense, sequential h loads -> LDS (swizzled), one
// barrier, 128 MFMAs/wave of 16x16x32.
__global__ __launch_bounds__(256) void pgemm(const float* __restrict__ h,
                                             const unsigned short* __restrict__ wc,
                                             unsigned short* __restrict__ Pb) {
  __shared__ short hl[16384];   // [64 rows][256 el] swz, 32 KB
  const int bid = blockIdx.x;
  const int tile = bid >> 1, ch = bid & 1;
  const int nb = tile * 64;
  const int t = threadIdx.x;
  const int lane = t & 63;
  const int wv = t >> 6;
  const int cl = lane & 15;
  const int q = lane >> 4;
  const int sx = (cl & 7) << 3;

  // stage h rows (sequential, coalesced): thread covers rows t>>3 and +32, piece t&7
  const int row0 = t >> 3, p0 = t & 7;
  const int row1 = row0 + 32;
  const int n0 = (nb + row0 < NN) ? nb + row0 : NN - 1;
  const int n1 = (nb + row1 < NN) ? nb + row1 : NN - 1;
  const int sw0e = (row0 & 7) << 3;
  const int sw1e = (row1 & 7) << 3;
#pragma unroll
  for (int c = 0; c < 4; ++c) {
    int4 v0 = cvt_row(h + (size_t)n0 * 256 + c * 64 + p0 * 8);
    int4 v1 = cvt_row(h + (size_t)n1 * 256 + c * 64 + p0 * 8);
    *(int4*)&hl[row0 * 256 + ((c * 64 + p0 * 8) ^ sw0e)] = v0;
    *(int4*)&hl[row1 * 256 + ((c * 64 + p0 * 8) ^ sw1e)] = v1;
  }
  LBAR();

  const unsigned short* wcp = wc + q * 4096 + (size_t)(ch * 256 + wv * 64 + cl) * 8;
  f32x4 acc[4][4];
#pragma unroll
  for (int i = 0; i < 4; ++i)
#pragma unroll
    for (int j = 0; j < 4; ++j) acc[i][j] = (f32x4){0.f, 0.f, 0.f, 0.f};

#pragma unroll
  for (int c = 0; c < 4; ++c)
#pragma unroll
    for (int ks = 0; ks < 2; ++ks) {
      half8 bf[4], fX[4];
#pragma unroll
      for (int j = 0; j < 4; ++j)
        bf[j] = *(const half8*)&hl[(j * 16 + cl) * 256 + ((c * 64 + ks * 32 + q * 8) ^ sx)];
#pragma unroll
      for (int i = 0; i < 4; ++i) fX[i] = ldg8(wcp + (c * 2 + ks) * 16384 + i * 128);
#pragma unroll
      for (int i = 0; i < 4; ++i)
#pragma unroll
        for (int j = 0; j < 4; ++j)
          acc[i][j] = __builtin_amdgcn_mfma_f32_16x16x32_f16(fX[i], bf[j], acc[i][j], 0, 0, 0);
    }

  // store fp16 P: D row m -> col mm = ch*256 + wv*64 + i*16 + q*4(+r), col n = node
#pragma unroll
  for (int i = 0; i < 4; ++i)
#pragma unroll
    for (int j = 0; j < 4; ++j) {
      int n = nb + cl + 16 * j;
      if (n < NN) {
        int mm = ch * 256 + wv * 64 + i * 16 + q * 4;
        uint2 w;
        w.x = pkrtz(acc[i][j][0], acc[i][j][1]);
        w.y = pkrtz(acc[i][j][2], acc[i][j][3]);
        *(uint2*)(Pb + (size_t)n * 512 + mm) = w;
      }
    }
}

// ---- edge kernel (P path): 64 edges/block, 256 threads, 3 blocks/CU ----
// GEMM1 -> 32 direct 8B P-gathers (D-layout, issued 32-deep before the feats
// barrier; land straight in acc) + 32 feat MFMAs from LDS. No staging dbuf, no
// GEMM1 barriers. GEMM2/LN/GEMM3/output = proven r5 code verbatim.
struct __align__(16) SMemN {
  short r1[16384];    // z1T [64][256]swz -> z2T [64][128]swz overlay
  short feats[4096];  // built features chunk [64 edges][64 K] swz
  float red[512];     // LN partials -> out staging (320f)
  _Float16 b1h[256], g1h[256], be1h[256];
  _Float16 b2h[128], g2h[128], be2h[128];
  float muv[16];
  float b3v[8];
  int spI[64], exI[64];
};  // ~45 KB -> 3 blocks/CU

__global__ __launch_bounds__(256, 3)
void edge_head_main(const float* __restrict__ x,
                    const int* __restrict__ spawn, const int* __restrict__ exist,
                    const float* __restrict__ insx, const int* __restrict__ insa,
                    const int* __restrict__ insc,
                    const float* __restrict__ b1, const float* __restrict__ g1,
                    const float* __restrict__ be1,
                    const float* __restrict__ b2, const float* __restrict__ g2,
                    const float* __restrict__ be2,
                    const float* __restrict__ b3, const float* __restrict__ mu,
                    const float* __restrict__ gammaP,
                    const unsigned short* __restrict__ w1f,
                    const unsigned short* __restrict__ w2sw,
                    const unsigned short* __restrict__ w3swg,
                    const unsigned short* __restrict__ Pb,
                    float* __restrict__ out) {
  __shared__ SMemN sm;
  const int t = threadIdx.x;
  const int base = blockIdx.x * 64;
  const int lane = t & 63;
  const int wv = t >> 6;
  const int cl = lane & 15;
  const int q = lane >> 4;
  const int sx = (cl & 7) << 3;

  // ---- const staging ----
  sm.b1h[t] = (_Float16)b1[t]; sm.g1h[t] = (_Float16)g1[t]; sm.be1h[t] = (_Float16)be1[t];
  if (t < 128) { sm.b2h[t] = (_Float16)b2[t]; sm.g2h[t] = (_Float16)g2[t]; sm.be2h[t] = (_Float16)be2[t]; }
  if (t < 16) sm.muv[t] = mu[t];
  if (t < 8) sm.b3v[t] = (t < 5) ? b3[t] : 0.f;
  if (t < 64) {
    int e = base + t; int ec = e < EE ? e : EE - 1;
    sm.spI[t] = spawn[ec]; sm.exI[t] = exist[ec];
  }
  const float gma = gammaP[0];

  LBAR();   // B0: indices + consts visible

  // ---- P gather bases (lane's edge for n-tile j is cl+16j) and 32 loads ----
  const unsigned short* pb1[4];
  const unsigned short* pb2[4];
#pragma unroll
  for (int j = 0; j < 4; ++j) {
    int n = cl + 16 * j;
    pb1[j] = Pb + (size_t)sm.spI[n] * 512 + wv * 64 + q * 4;
    pb2[j] = Pb + (size_t)sm.exI[n] * 512 + 256 + wv * 64 + q * 4;
  }
  half4 p1v[4][4], p2v[4][4];   // [i][j] : channels wv*64+i*16+q*4..+3, edge cl+16j
#pragma unroll
  for (int i = 0; i < 4; ++i)
#pragma unroll
    for (int j = 0; j < 4; ++j) p1v[i][j] = *(const half4*)(pb1[j] + i * 16);
#pragma unroll
  for (int i = 0; i < 4; ++i)
#pragma unroll
    for (int j = 0; j < 4; ++j) p2v[i][j] = *(const half4*)(pb2[j] + i * 16);

  // ---- wave 0: build features chunk (K rows 512..575) -> sm.feats ----
  if (t < 64) {
    int e = base + t; int ec = e < EE ? e : EE - 1;
    float ix0 = insx[ec * 3], ix1 = insx[ec * 3 + 1], ix2 = insx[ec * 3 + 2];
    int nd = sm.exI[t];
    float dx = ix0 - x[nd * 3], dy = ix1 - x[nd * 3 + 1], dz = ix2 - x[nd * 3 + 2];
    float d = fmaxf(sqrtf(dx * dx + dy * dy + dz * dz), 1e-6f);
    int k1 = 16 + insa[ec], k2 = 32 + insc[ec];
    short* rp = &sm.feats[t * 64];
    const int sw = t & 7;
    float rb[16];
#pragma unroll
    for (int k = 0; k < 16; ++k) { float dd = d - sm.muv[k]; rb[k] = __expf(-gma * dd * dd); }
    uint4 ua, ub;
    ua.x = pkrtz(rb[0], rb[1]);  ua.y = pkrtz(rb[2], rb[3]);
    ua.z = pkrtz(rb[4], rb[5]);  ua.w = pkrtz(rb[6], rb[7]);
    ub.x = pkrtz(rb[8], rb[9]);  ub.y = pkrtz(rb[10], rb[11]);
    ub.z = pkrtz(rb[12], rb[13]); ub.w = pkrtz(rb[14], rb[15]);
    *(int4*)&rp[(0 ^ sw) * 8] = *(int4*)&ua;
    *(int4*)&rp[(1 ^ sw) * 8] = *(int4*)&ub;
    const int4 z4 = {0, 0, 0, 0};
#pragma unroll
    for (int g = 2; g < 8; ++g) *(int4*)&rp[(g ^ sw) * 8] = z4;
    rp[((k1 >> 3) ^ sw) * 8 + (k1 & 7)] = (short)0x3C00;   // fp16 1.0
    rp[((k2 >> 3) ^ sw) * 8 + (k2 & 7)] = (short)0x3C00;
  }

  LBAR();   // feats visible (P loads still in flight — lgkm-only barrier)

  // ---- acc = P1 + P2 (f32 adds of gathered fp16), then 32 feat MFMAs ----
  f32x4 acc[4][4];
#pragma unroll
  for (int i = 0; i < 4; ++i)
#pragma unroll
    for (int j = 0; j < 4; ++j) {
      f32x4 a;
      a[0] = (float)p1v[i][j][0] + (float)p2v[i][j][0];
      a[1] = (float)p1v[i][j][1] + (float)p2v[i][j][1];
      a[2] = (float)p1v[i][j][2] + (float)p2v[i][j][2];
      a[3] = (float)p1v[i][j][3] + (float)p2v[i][j][3];
      acc[i][j] = a;
    }
  {
    const unsigned short* w1fp = w1f + q * 2048 + wv * 512 + cl * 8;
#pragma unroll
    for (int ks = 0; ks < 2; ++ks) {
      half8 bf[4], fX[4];
#pragma unroll
      for (int j = 0; j < 4; ++j)
        bf[j] = *(const half8*)&sm.feats[(j * 16 + cl) * 64 + ((ks * 32 + q * 8) ^ sx)];
#pragma unroll
      for (int i = 0; i < 4; ++i) fX[i] = ldg8(w1fp + ks * 8192 + i * 128);
#pragma unroll
      for (int i = 0; i < 4; ++i)
#pragma unroll
        for (int j = 0; j < 4; ++j)
          acc[i][j] = __builtin_amdgcn_mfma_f32_16x16x32_f16(fX[i], bf[j], acc[i][j], 0, 0, 0);
    }
  }

  // ---- +b1, LN over 256 channels, SiLU, pack z1T (r5 verbatim) ----
  f32x2 bb1[4][2];
#pragma unroll
  for (int i = 0; i < 4; ++i) {
    half4 b4 = *(const half4*)&sm.b1h[wv * 64 + i * 16 + q * 4];
    bb1[i][0] = (f32x2){(float)b4[0], (float)b4[1]};
    bb1[i][1] = (f32x2){(float)b4[2], (float)b4[3]};
  }
  float S1arr[4], Q1arr[4];
#pragma unroll
  for (int j = 0; j < 4; ++j) {
    f32x2 S2 = (f32x2){0.f, 0.f}, Q2 = (f32x2){0.f, 0.f};
#pragma unroll
    for (int i = 0; i < 4; ++i) {
      f32x2 v0 = (f32x2){acc[i][j][0], acc[i][j][1]} + bb1[i][0];
      f32x2 v1 = (f32x2){acc[i][j][2], acc[i][j][3]} + bb1[i][1];
      acc[i][j][0] = v0[0]; acc[i][j][1] = v0[1];
      acc[i][j][2] = v1[0]; acc[i][j][3] = v1[1];
      S2 += v0 + v1;
      Q2 += v0 * v0;
      Q2 += v1 * v1;
    }
    float S = S2[0] + S2[1], Q = Q2[0] + Q2[1];
    S += __shfl_xor(S, 16); S += __shfl_xor(S, 32);
    Q += __shfl_xor(Q, 16); Q += __shfl_xor(Q, 32);
    S1arr[j] = S; Q1arr[j] = Q;
  }
  if (q == 0) {
#pragma unroll
    for (int j = 0; j < 4; ++j) {
      sm.red[wv * 64 + j * 16 + cl] = S1arr[j];
      sm.red[256 + wv * 64 + j * 16 + cl] = Q1arr[j];
    }
  }
  LBAR();
  f32x2 rs1[4], mr1[4];
#pragma unroll
  for (int j = 0; j < 4; ++j) {
    int m = j * 16 + cl;
    float S = sm.red[m] + sm.red[64 + m] + sm.red[128 + m] + sm.red[192 + m];
    float Q = sm.red[256 + m] + sm.red[320 + m] + sm.red[384 + m] + sm.red[448 + m];
    float mn = S * (1.f / 256.f);
    float rs = rsqrtf(Q * (1.f / 256.f) - mn * mn + LN_EPS);
    rs1[j] = (f32x2){rs, rs};
    mr1[j] = (f32x2){-mn * rs, -mn * rs};
  }
#pragma unroll
  for (int i = 0; i < 4; ++i) {
    half4 g4 = *(const half4*)&sm.g1h[wv * 64 + i * 16 + q * 4];
    half4 e4 = *(const half4*)&sm.be1h[wv * 64 + i * 16 + q * 4];
    f32x2 gg0 = (f32x2){(float)g4[0], (float)g4[1]}, gg1 = (f32x2){(float)g4[2], (float)g4[3]};
    f32x2 ee0 = (f32x2){(float)e4[0], (float)e4[1]}, ee1 = (f32x2){(float)e4[2], (float)e4[3]};
#pragma unroll
    for (int j = 0; j < 4; ++j) {
      f32x2 v0 = (f32x2){acc[i][j][0], acc[i][j][1]};
      f32x2 v1 = (f32x2){acc[i][j][2], acc[i][j][3]};
      f32x2 t0 = v0 * rs1[j] + mr1[j];
      f32x2 t1 = v1 * rs1[j] + mr1[j];
      f32x2 y0 = t0 * gg0 + ee0;
      f32x2 y1 = t1 * gg1 + ee1;
      float s0 = fast_silu(y0[0]), s1 = fast_silu(y0[1]);
      float s2 = fast_silu(y1[0]), s3 = fast_silu(y1[1]);
      uint2 w; w.x = pkrtz(s0, s1); w.y = pkrtz(s2, s3);
      int m = j * 16 + cl;
      int k0 = wv * 64 + i * 16 + q * 4;
      *(uint2*)&sm.r1[m * 256 + (k0 ^ ((m & 7) << 3))] = w;   // z1T swz
    }
  }
  LBAR();   // z1T visible

  half8 af3[4];
#pragma unroll
  for (int ks = 0; ks < 4; ++ks)
    af3[ks] = ldg8(w3swg + (ks * 4 + q) * 128 + cl * 8);

  // ---- GEMM2 (r5 verbatim) ----
  const unsigned short* w2p = w2sw + q * 1024 + wv * 256 + cl * 8;
  f32x4 acc2[2][4];
#pragma unroll
  for (int i = 0; i < 2; ++i)
#pragma unroll
    for (int j = 0; j < 4; ++j) acc2[i][j] = (f32x4){0.f, 0.f, 0.f, 0.f};
#pragma unroll
  for (int c2 = 0; c2 < 4; ++c2) {
#pragma unroll
    for (int ks = 0; ks < 2; ++ks) {
      half8 a0 = ldg8(w2p + c2 * 8192 + ks * 4096);
      half8 a1 = ldg8(w2p + c2 * 8192 + ks * 4096 + 128);
      half8 bf[4];
#pragma unroll
      for (int j = 0; j < 4; ++j)
        bf[j] = *(const half8*)&sm.r1[(j * 16 + cl) * 256 + ((c2 * 64 + ks * 32 + q * 8) ^ sx)];
#pragma unroll
      for (int j = 0; j < 4; ++j) {
        acc2[0][j] = __builtin_amdgcn_mfma_f32_16x16x32_f16(a0, bf[j], acc2[0][j], 0, 0, 0);
        acc2[1][j] = __builtin_amdgcn_mfma_f32_16x16x32_f16(a1, bf[j], acc2[1][j], 0, 0, 0);
      }
    }
  }

  // ---- +b2, LN over 128, SiLU, pack z2T (r5 verbatim) ----
  f32x2 bb2[2][2];
#pragma unroll
  for (int i = 0; i < 2; ++i) {
    half4 b4 = *(const half4*)&sm.b2h[wv * 32 + i * 16 + q * 4];
    bb2[i][0] = (f32x2){(float)b4[0], (float)b4[1]};
    bb2[i][1] = (f32x2){(float)b4[2], (float)b4[3]};
  }
  float S2arr[4], Q2arr[4];
#pragma unroll
  for (int j = 0; j < 4; ++j) {
    f32x2 S2 = (f32x2){0.f, 0.f}, Q2 = (f32x2){0.f, 0.f};
#pragma unroll
    for (int i = 0; i < 2; ++i) {
      f32x2 v0 = (f32x2){acc2[i][j][0], acc2[i][j][1]} + bb2[i][0];
      f32x2 v1 = (f32x2){acc2[i][j][2], acc2[i][j][3]} + bb2[i][1];
      acc2[i][j][0] = v0[0]; acc2[i][j][1] = v0[1];
      acc2[i][j][2] = v1[0]; acc2[i][j][3] = v1[1];
      S2 += v0 + v1;
      Q2 += v0 * v0;
      Q2 += v1 * v1;
    }
    float S = S2[0] + S2[1], Q = Q2[0] + Q2[1];
    S += __shfl_xor(S, 16); S += __shfl_xor(S, 32);
    Q += __shfl_xor(Q, 16); Q += __shfl_xor(Q, 32);
    S2arr[j] = S; Q2arr[j] = Q;
  }
  if (q == 0) {
#pragma unroll
    for (int j = 0; j < 4; ++j) {
      sm.red[wv * 64 + j * 16 + cl] = S2arr[j];
      sm.red[256 + wv * 64 + j * 16 + cl] = Q2arr[j];
    }
  }
  LBAR();
  f32x2 rs2[4], mr2[4];
#pragma unroll
  for (int j = 0; j < 4; ++j) {
    int m = j * 16 + cl;
    float S = sm.red[m] + sm.red[64 + m] + sm.red[128 + m] + sm.red[192 + m];
    float Q = sm.red[256 + m] + sm.red[320 + m] + sm.red[384 + m] + sm.red[448 + m];
    float mn = S * (1.f / 128.f);
    float rs = rsqrtf(Q * (1.f / 128.f) - mn * mn + LN_EPS);
    rs2[j] = (f32x2){rs, rs};
    mr2[j] = (f32x2){-mn * rs, -mn * rs};
  }
#pragma unroll
  for (int i = 0; i < 2; ++i) {
    half4 g4 = *(const half4*)&sm.g2h[wv * 32 + i * 16 + q * 4];
    half4 e4 = *(const half4*)&sm.be2h[wv * 32 + i * 16 + q * 4];
    f32x2 gg0 = (f32x2){(float)g4[0], (float)g4[1]}, gg1 = (f32x2){(float)g4[2], (float)g4[3]};
    f32x2 ee0 = (f32x2){(float)e4[0], (float)e4[1]}, ee1 = (f32x2){(float)e4[2], (float)e4[3]};
#pragma unroll
    for (int j = 0; j < 4; ++j) {
      f32x2 v0 = (f32x2){acc2[i][j][0], acc2[i][j][1]};
      f32x2 v1 = (f32x2){acc2[i][j][2], acc2[i][j][3]};
      f32x2 t0 = v0 * rs2[j] + mr2[j];
      f32x2 t1 = v1 * rs2[j] + mr2[j];
      f32x2 y0 = t0 * gg0 + ee0;
      f32x2 y1 = t1 * gg1 + ee1;
      float s0 = fast_silu(y0[0]), s1 = fast_silu(y0[1]);
      float s2 = fast_silu(y1[0]), s3 = fast_silu(y1[1]);
      uint2 w; w.x = pkrtz(s0, s1); w.y = pkrtz(s2, s3);
      int m = j * 16 + cl;
      int k0 = wv * 32 + i * 16 + q * 4;
      *(uint2*)&sm.r1[m * 128 + (k0 ^ ((m & 7) << 3))] = w;   // z2T swz
    }
  }
  LBAR();   // z2T visible

  // ---- GEMM3 + staged coalesced output (r5 verbatim) ----
  f32x4 a3 = (f32x4){0.f, 0.f, 0.f, 0.f};
  const int m3 = wv * 16 + cl;
  const int sx3 = (m3 & 7) << 3;
#pragma unroll
  for (int ks = 0; ks < 4; ++ks) {
    half8 bfv = *(const half8*)&sm.r1[m3 * 128 + ((ks * 32 + q * 8) ^ sx3)];
    a3 = __builtin_amdgcn_mfma_f32_16x16x32_f16(af3[ks], bfv, a3, 0, 0, 0);
  }
#pragma unroll
  for (int r = 0; r < 4; ++r) {
    int o = q * 4 + r;
    if (o < 5) sm.red[m3 * 5 + o] = a3[r] + sm.b3v[o];
  }
  LBAR();
  if (t < 80) {
    size_t g = (size_t)base * 5 + (size_t)t * 4;
    if (g + 4 <= (size_t)EE * 5) {
      *(float4*)(out + g) = *(const float4*)&sm.red[t * 4];
    } else {
#pragma unroll
      for (int u = 0; u < 4; ++u)
        if (g + u < (size_t)EE * 5) out[g + u] = sm.red[t * 4 + u];
    }
  }
}

// =======================  FALLBACK PATH (r5, f32-h gathers)  =======================
// Used only if ws_size < P-path requirement. Proven r5 structure, use_hb=0.

__global__ __launch_bounds__(256) void prep_fb(const float* __restrict__ W1,
                                               const float* __restrict__ W2,
                                               const float* __restrict__ W3,
                                               unsigned short* __restrict__ w1sw,
                                               unsigned short* __restrict__ w2sw,
                                               unsigned short* __restrict__ w3sw) {
  int t = blockIdx.x * 256 + threadIdx.x;
  if (t < 147456) {
    int chunk = t >> 14, rem = t & 16383;
    int kq = rem >> 11, n = (rem >> 3) & 255, j = rem & 7;
    int k = (chunk << 6) + (kq << 3) + j;
    w1sw[t] = f2h((k < 551) ? W1[k * 256 + n] : 0.f);
  } else if (t < 180224) {
    int t2 = t - 147456;
    int chunk = t2 >> 13, rem = t2 & 8191;
    int kq = rem >> 10, n = (rem >> 3) & 127, j = rem & 7;
    int k = (chunk << 6) + (kq << 3) + j;
    w2sw[t2] = f2h(W2[k * 128 + n]);
  } else if (t < 182272) {
    int t3 = t - 180224;
    int kq = t3 >> 7, o = (t3 >> 3) & 15, j = t3 & 7;
    int k = (kq << 3) + j;
    w3sw[t3] = f2h((o < 5) ? W3[k * 5 + o] : 0.f);
  }
}

struct __align__(16) SMemF {
  short r1[16384];
  short feats[4096];
  float red[512];
  _Float16 b1h[256], g1h[256], be1h[256];
  _Float16 b2h[128], g2h[128], be2h[128];
  float muv[16];
  float b3v[8];
  int spI[64], exI[64];
};

__global__ __launch_bounds__(256, 3)
void edge_head_fb(const float* __restrict__ h, const float* __restrict__ x,
                  const int* __restrict__ spawn, const int* __restrict__ exist,
                  const float* __restrict__ insx, const int* __restrict__ insa,
                  const int* __restrict__ insc,
                  const float* __restrict__ b1, const float* __restrict__ g1,
                  const float* __restrict__ be1,
                  const float* __restrict__ b2, const float* __restrict__ g2,
                  const float* __restrict__ be2,
                  const float* __restrict__ b3, const float* __restrict__ mu,
                  const float* __restrict__ gammaP,
                  const unsigned short* __restrict__ w1sw,
                  const unsigned short* __restrict__ w2sw,
                  const unsigned short* __restrict__ w3swg,
                  float* __restrict__ out) {
  __shared__ SMemF sm;
  const int t = threadIdx.x;
  const int base = blockIdx.x * 64;
  const int lane = t & 63;
  const int wv = t >> 6;
  const int cl = lane & 15;
  const int q = lane >> 4;
  const int sx = (cl & 7) << 3;

  sm.b1h[t] = (_Float16)b1[t]; sm.g1h[t] = (_Float16)g1[t]; sm.be1h[t] = (_Float16)be1[t];
  if (t < 128) { sm.b2h[t] = (_Float16)b2[t]; sm.g2h[t] = (_Float16)g2[t]; sm.be2h[t] = (_Float16)be2[t]; }
  if (t < 16) sm.muv[t] = mu[t];
  if (t < 8) sm.b3v[t] = (t < 5) ? b3[t] : 0.f;
  if (t < 64) {
    int e = base + t; int ec = e < EE ? e : EE - 1;
    sm.spI[t] = spawn[ec]; sm.exI[t] = exist[ec];
  }
  const float gma = gammaP[0];
  LBAR();

  float dreg = 0.f;
  int k1 = 16, k2 = 32;
  if (t < 64) {
    int e = base + t; int ec = e < EE ? e : EE - 1;
    float ix0 = insx[ec * 3], ix1 = insx[ec * 3 + 1], ix2 = insx[ec * 3 + 2];
    int nd = sm.exI[t];
    float dx = ix0 - x[nd * 3], dy = ix1 - x[nd * 3 + 1], dz = ix2 - x[nd * 3 + 2];
    dreg = fmaxf(sqrtf(dx * dx + dy * dy + dz * dz), 1e-6f);
    k1 = 16 + insa[ec]; k2 = 32 + insc[ec];
  }

  const int row0 = t >> 3, p0 = t & 7;
  const int row1 = row0 + 32;
  const int sw0 = ((p0 ^ (row0 & 7)) << 3);
  const int sw1 = ((p0 ^ (row1 & 7)) << 3);

  const float* bSp0 = h + (size_t)sm.spI[row0] * HIDD + p0 * 8;
  const float* bSp1 = h + (size_t)sm.spI[row1] * HIDD + p0 * 8;
  const float* bEx0 = h + (size_t)sm.exI[row0] * HIDD + p0 * 8;
  const float* bEx1 = h + (size_t)sm.exI[row1] * HIDD + p0 * 8;

  int4 pS0, pS1, pS2, pS3;
#define GLOAD2F(ph) do {                                                \
    const float* b0_ = ((ph) < 2) ? bSp0 : bEx0;                        \
    const float* b1_ = ((ph) < 2) ? bSp1 : bEx1;                        \
    const int ce_ = ((ph) & 1) * 128;                                   \
    pS0 = cvt_row(b0_ + ce_);                                           \
    pS1 = cvt_row(b1_ + ce_);                                           \
    pS2 = cvt_row(b0_ + ce_ + 64);                                      \
    pS3 = cvt_row(b1_ + ce_ + 64);                                      \
  } while (0)

  GLOAD2F(0);
  *(int4*)&sm.r1[row0 * 64 + sw0] = pS0;
  *(int4*)&sm.r1[row1 * 64 + sw1] = pS1;
  *(int4*)&sm.r1[4096 + row0 * 64 + sw0] = pS2;
  *(int4*)&sm.r1[4096 + row1 * 64 + sw1] = pS3;
  GLOAD2F(1);

  const unsigned short* w1p = w1sw + q * 2048 + wv * 512 + cl * 8;

  if (t < 64) {
    short* rp = &sm.feats[t * 64];
    const int sw = t & 7;
    float rb[16];
#pragma unroll
    for (int k = 0; k < 16; ++k) { float dd = dreg - sm.muv[k]; rb[k] = __expf(-gma * dd * dd); }
    uint4 ua, ub;
    ua.x = pkrtz(rb[0], rb[1]);  ua.y = pkrtz(rb[2], rb[3]);
    ua.z = pkrtz(rb[4], rb[5]);  ua.w = pkrtz(rb[6], rb[7]);
    ub.x = pkrtz(rb[8], rb[9]);  ub.y = pkrtz(rb[10], rb[11]);
    ub.z = pkrtz(rb[12], rb[13]); ub.w = pkrtz(rb[14], rb[15]);
    *(int4*)&rp[(0 ^ sw) * 8] = *(int4*)&ua;
    *(int4*)&rp[(1 ^ sw) * 8] = *(int4*)&ub;
    const int4 z4 = {0, 0, 0, 0};
#pragma unroll
    for (int g = 2; g < 8; ++g) *(int4*)&rp[(g ^ sw) * 8] = z4;
    rp[((k1 >> 3) ^ sw) * 8 + (k1 & 7)] = (short)0x3C00;
    rp[((k2 >> 3) ^ sw) * 8 + (k2 & 7)] = (short)0x3C00;
  }
  LBAR();

  f32x4 acc[4][4];
#pragma unroll
  for (int i = 0; i < 4; ++i)
#pragma unroll
    for (int j = 0; j < 4; ++j) acc[i][j] = (f32x4){0.f, 0.f, 0.f, 0.f};

#pragma unroll
  for (int p = 0; p < 4; ++p) {
    if (p < 3) {
      const int nb = ((p + 1) & 1) * 8192;
      *(int4*)&sm.r1[nb + row0 * 64 + sw0] = pS0;
      *(int4*)&sm.r1[nb + row1 * 64 + sw1] = pS1;
      *(int4*)&sm.r1[nb + 4096 + row0 * 64 + sw0] = pS2;
      *(int4*)&sm.r1[nb + 4096 + row1 * 64 + sw1] = pS3;
      if (p < 2) GLOAD2F(p + 2);
    }
    const int cb = (p & 1) * 8192;
#pragma unroll
    for (int ch = 0; ch < 2; ++ch) {
      const unsigned short* wp = w1p + (2 * p + ch) * 16384;
#pragma unroll
      for (int ks = 0; ks < 2; ++ks) {
        half8 bf[4], fX[4];
#pragma unroll
        for (int j = 0; j < 4; ++j)
          bf[j] = *(const half8*)&sm.r1[cb + ch * 4096 + (j * 16 + cl) * 64 + ((ks * 32 + q * 8) ^ sx)];
#pragma unroll
        for (int i = 0; i < 4; ++i) fX[i] = ldg8(wp + ks * 8192 + i * 128);
#pragma unroll
        for (int i = 0; i < 4; ++i)
#pragma unroll
          for (int j = 0; j < 4; ++j)
            acc[i][j] = __builtin_amdgcn_mfma_f32_16x16x32_f16(fX[i], bf[j], acc[i][j], 0, 0, 0);
      }
    }
    if (p < 3) LBAR();
  }
#undef GLOAD2F

  {
    const unsigned short* wp = w1p + 8 * 16384;
#pragma unroll
    for (int ks = 0; ks < 2; ++ks) {
      half8 bf[4], fX[4];
#pragma unroll
      for (int j = 0; j < 4; ++j)
        bf[j] = *(const half8*)&sm.feats[(j * 16 + cl) * 64 + ((ks * 32 + q * 8) ^ sx)];
#pragma unroll
      for (int i = 0; i < 4; ++i) fX[i] = ldg8(wp + ks * 8192 + i * 128);
#pragma unroll
      for (int i = 0; i < 4; ++i)
#pragma unroll
        for (int j = 0; j < 4; ++j)
          acc[i][j] = __builtin_amdgcn_mfma_f32_16x16x32_f16(fX[i], bf[j], acc[i][j], 0, 0, 0);
    }
  }

  f32x2 bb1[4][2];
#pragma unroll
  for (int i = 0; i < 4; ++i) {
    half4 b4 = *(const half4*)&sm.b1h[wv * 64 + i * 16 + q * 4];
    bb1[i][0] = (f32x2){(float)b4[0], (float)b4[1]};
    bb1[i][1] = (f32x2){(float)b4[2], (float)b4[3]};
  }
  float S1arr[4], Q1arr[4];
#pragma unroll
  for (int j = 0; j < 4; ++j) {
    f32x2 S2 = (f32x2){0.f, 0.f}, Q2 = (f32x2){0.f, 0.f};
#pragma unroll
    for (int i = 0; i < 4; ++i) {
      f32x2 v0 = (f32x2){acc[i][j][0], acc[i][j][1]} + bb1[i][0];
      f32x2 v1 = (f32x2){acc[i][j][2], acc[i][j][3]} + bb1[i][1];
      acc[i][j][0] = v0[0]; acc[i][j][1] = v0[1];
      acc[i][j][2] = v1[0]; acc[i][j][3] = v1[1];
      S2 += v0 + v1; Q2 += v0 * v0; Q2 += v1 * v1;
    }
    float S = S2[0] + S2[1], Q = Q2[0] + Q2[1];
    S += __shfl_xor(S, 16); S += __shfl_xor(S, 32);
    Q += __shfl_xor(Q, 16); Q += __shfl_xor(Q, 32);
    S1arr[j] = S; Q1arr[j] = Q;
  }
  if (q == 0) {
#pragma unroll
    for (int j = 0; j < 4; ++j) {
      sm.red[wv * 64 + j * 16 + cl] = S1arr[j];
      sm.red[256 + wv * 64 + j * 16 + cl] = Q1arr[j];
    }
  }
  LBAR();
  f32x2 rs1[4], mr1[4];
#pragma unroll
  for (int j = 0; j < 4; ++j) {
    int m = j * 16 + cl;
    float S = sm.red[m] + sm.red[64 + m] + sm.red[128 + m] + sm.red[192 + m];
    float Q = sm.red[256 + m] + sm.red[320 + m] + sm.red[384 + m] + sm.red[448 + m];
    float mn = S * (1.f / 256.f);
    float rs = rsqrtf(Q * (1.f / 256.f) - mn * mn + LN_EPS);
    rs1[j] = (f32x2){rs, rs};
    mr1[j] = (f32x2){-mn * rs, -mn * rs};
  }
#pragma unroll
  for (int i = 0; i < 4; ++i) {
    half4 g4 = *(const half4*)&sm.g1h[wv * 64 + i * 16 + q * 4];
    half4 e4 = *(const half4*)&sm.be1h[wv * 64 + i * 16 + q * 4];
    f32x2 gg0 = (f32x2){(float)g4[0], (float)g4[1]}, gg1 = (f32x2){(float)g4[2], (float)g4[3]};
    f32x2 ee0 = (f32x2){(float)e4[0], (float)e4[1]}, ee1 = (f32x2){(float)e4[2], (float)e4[3]};
#pragma unroll
    for (int j = 0; j < 4; ++j) {
      f32x2 v0 = (f32x2){acc[i][j][0], acc[i][j][1]};
      f32x2 v1 = (f32x2){acc[i][j][2], acc[i][j][3]};
      f32x2 t0 = v0 * rs1[j] + mr1[j];
      f32x2 t1 = v1 * rs1[j] + mr1[j];
      f32x2 y0 = t0 * gg0 + ee0;
      f32x2 y1 = t1 * gg1 + ee1;
      float s0 = fast_silu(y0[0]), s1 = fast_silu(y0[1]);
      float s2 = fast_silu(y1[0]), s3 = fast_silu(y1[1]);
      uint2 w; w.x = pkrtz(s0, s1); w.y = pkrtz(s2, s3);
      int m = j * 16 + cl;
      int k0 = wv * 64 + i * 16 + q * 4;
      *(uint2*)&sm.r1[m * 256 + (k0 ^ ((m & 7) << 3))] = w;
    }
  }
  LBAR();

  half8 af3[4];
#pragma unroll
  for (int ks = 0; ks < 4; ++ks)
    af3[ks] = ldg8(w3swg + (ks * 4 + q) * 128 + cl * 8);

  const unsigned short* w2p = w2sw + q * 1024 + wv * 256 + cl * 8;
  f32x4 acc2[2][4];
#pragma unroll
  for (int i = 0; i < 2; ++i)
#pragma unroll
    for (int j = 0; j < 4; ++j) acc2[i][j] = (f32x4){0.f, 0.f, 0.f, 0.f};
#pragma unroll
  for (int c2 = 0; c2 < 4; ++c2) {
#pragma unroll
    for (int ks = 0; ks < 2; ++ks) {
      half8 a0 = ldg8(w2p + c2 * 8192 + ks * 4096);
      half8 a1 = ldg8(w2p + c2 * 8192 + ks * 4096 + 128);
      half8 bf[4];
#pragma unroll
      for (int j = 0; j < 4; ++j)
        bf[j] = *(const half8*)&sm.r1[(j * 16 + cl) * 256 + ((c2 * 64 + ks * 32 + q * 8) ^ sx)];
#pragma unroll
      for (int j = 0; j < 4; ++j) {
        acc2[0][j] = __builtin_amdgcn_mfma_f32_16x16x32_f16(a0, bf[j], acc2[0][j], 0, 0, 0);
        acc2[1][j] = __builtin_amdgcn_mfma_f32_16x16x32_f16(a1, bf[j], acc2[1][j], 0, 0, 0);
      }
    }
  }

  f32x2 bb2[2][2];
#pragma unroll
  for (int i = 0; i < 2; ++i) {
    half4 b4 = *(const half4*)&sm.b2h[wv * 32 + i * 16 + q * 4];
    bb2[i][0] = (f32x2){(float)b4[0], (float)b4[1]};
    bb2[i][1] = (f32x2){(float)b4[2], (float)b4[3]};
  }
  float S2arr[4], Q2arr[4];
#pragma unroll
  for (int j = 0; j < 4; ++j) {
    f32x2 S2 = (f32x2){0.f, 0.f}, Q2 = (f32x2){0.f, 0.f};
#pragma unroll
    for (int i = 0; i < 2; ++i) {
      f32x2 v0 = (f32x2){acc2[i][j][0], acc2[i][j][1]} + bb2[i][0];
      f32x2 v1 = (f32x2){acc2[i][j][2], acc2[i][j][3]} + bb2[i][1];
      acc2[i][j][0] = v0[0]; acc2[i][j][1] = v0[1];
      acc2[i][j][2] = v1[0]; acc2[i][j][3] = v1[1];
      S2 += v0 + v1; Q2 += v0 * v0; Q2 += v1 * v1;
    }
    float S = S2[0] + S2[1], Q = Q2[0] + Q2[1];
    S += __shfl_xor(S, 16); S += __shfl_xor(S, 32);
    Q += __shfl_xor(Q, 16); Q += __shfl_xor(Q, 32);
    S2arr[j] = S; Q2arr[j] = Q;
  }
  if (q == 0) {
#pragma unroll
    for (int j = 0; j < 4; ++j) {
      sm.red[wv * 64 + j * 16 + cl] = S2arr[j];
      sm.red[256 + wv * 64 + j * 16 + cl] = Q2arr[j];
    }
  }
  LBAR();
  f32x2 rs2[4], mr2[4];
#pragma unroll
  for (int j = 0; j < 4; ++j) {
    int m = j * 16 + cl;
    float S = sm.red[m] + sm.red[64 + m] + sm.red[128 + m] + sm.red[192 + m];
    float Q = sm.red[256 + m] + sm.red[320 + m] + sm.red[384 + m] + sm.red[448 + m];
    float mn = S * (1.f / 128.f);
    float rs = rsqrtf(Q * (1.f / 128.f) - mn * mn + LN_EPS);
    rs2[j] = (f32x2){rs, rs};
    mr2[j] = (f32x2){-mn * rs, -mn * rs};
  }
#pragma unroll
  for (int i = 0; i < 2; ++i) {
    half4 g4 = *(const half4*)&sm.g2h[wv * 32 + i * 16 + q * 4];
    half4 e4 = *(const half4*)&sm.be2h[wv * 32 + i * 16 + q * 4];
    f32x2 gg0 = (f32x2){(float)g4[0], (float)g4[1]}, gg1 = (f32x2){(float)g4[2], (float)g4[3]};
    f32x2 ee0 = (f32x2){(float)e4[0], (float)e4[1]}, ee1 = (f32x2){(float)e4[2], (float)e4[3]};
#pragma unroll
    for (int j = 0; j < 4; ++j) {
      f32x2 v0 = (f32x2){acc2[i][j][0], acc2[i][j][1]};
      f32x2 v1 = (f32x2){acc2[i][j][2], acc2[i][j][3]};
      f32x2 t0 = v0 * rs2[j] + mr2[j];
      f32x2 t1 = v1 * rs2[j] + mr2[j];
      f32x2 y0 = t0 * gg0 + ee0;
      f32x2 y1 = t1 * gg1 + ee1;
      float s0 = fast_silu(y0[0]), s1 = fast_silu(y0[1]);
      float s2 = fast_silu(y1[0]), s3 = fast_silu(y1[1]);
      uint2 w; w.x = pkrtz(s0, s1); w.y = pkrtz(s2, s3);
      int m = j * 16 + cl;
      int k0 = wv * 32 + i * 16 + q * 4;
      *(uint2*)&sm.r1[m * 128 + (k0 ^ ((m & 7) << 3))] = w;
    }
  }
  LBAR();

  f32x4 a3 = (f32x4){0.f, 0.f, 0.f, 0.f};
  const int m3 = wv * 16 + cl;
  const int sx3 = (m3 & 7) << 3;
#pragma unroll
  for (int ks = 0; ks < 4; ++ks) {
    half8 bfv = *(const half8*)&sm.r1[m3 * 128 + ((ks * 32 + q * 8) ^ sx3)];
    a3 = __builtin_amdgcn_mfma_f32_16x16x32_f16(af3[ks], bfv, a3, 0, 0, 0);
  }
#pragma unroll
  for (int r = 0; r < 4; ++r) {
    int o = q * 4 + r;
    if (o < 5) sm.red[m3 * 5 + o] = a3[r] + sm.b3v[o];
  }
  LBAR();
  if (t < 80) {
    size_t g = (size_t)base * 5 + (size_t)t * 4;
    if (g + 4 <= (size_t)EE * 5) {
      *(float4*)(out + g) = *(const float4*)&sm.red[t * 4];
    } else {
#pragma unroll
      for (int u = 0; u < 4; ++u)
        if (g + u < (size_t)EE * 5) out[g + u] = sm.red[t * 4 + u];
    }
  }
}

extern "C" void kernel_launch(void* const* d_in, const int* in_sizes, int n_in,
                              void* d_out, int out_size, void* d_ws, size_t ws_size,
                              hipStream_t stream) {
  const float* h    = (const float*)d_in[0];
  const float* x    = (const float*)d_in[1];
  const int* spawn  = (const int*)d_in[2];
  const int* exist  = (const int*)d_in[3];
  const float* insx = (const float*)d_in[4];
  const int* insa   = (const int*)d_in[5];
  const int* insc   = (const int*)d_in[6];
  const float* W1   = (const float*)d_in[7];
  const float* b1   = (const float*)d_in[8];
  const float* g1   = (const float*)d_in[9];
  const float* be1  = (const float*)d_in[10];
  const float* W2   = (const float*)d_in[11];
  const float* b2   = (const float*)d_in[12];
  const float* g2   = (const float*)d_in[13];
  const float* be2  = (const float*)d_in[14];
  const float* W3   = (const float*)d_in[15];
  const float* b3   = (const float*)d_in[16];
  const float* mu   = (const float*)d_in[17];
  const float* gma  = (const float*)d_in[18];

  const size_t needP = 364544ull + (size_t)NN * 512 * 2;   // weights + fp16 P
  if (ws_size >= needP) {
    unsigned short* wc   = (unsigned short*)d_ws;   // 131072 el
    unsigned short* w1f  = wc + 131072;             // 16384 el
    unsigned short* w2sw = w1f + 16384;             // 32768 el
    unsigned short* w3sw = w2sw + 32768;            // 2048 el
    unsigned short* Pb   = w3sw + 2048;             // NN*512 el fp16
    prep_w<<<712, 256, 0, stream>>>(W1, W2, W3, wc, w1f, w2sw, w3sw);
    pgemm<<<3126, 256, 0, stream>>>(h, wc, Pb);
    edge_head_main<<<7813, 256, 0, stream>>>(x, spawn, exist, insx, insa, insc,
                                             b1, g1, be1, b2, g2, be2, b3, mu, gma,
                                             w1f, w2sw, w3sw, Pb, (float*)d_out);
  } else {
    unsigned short* w1sw = (unsigned short*)d_ws;   // 147456 el
    unsigned short* w2sw = w1sw + 147456;           // 32768 el
    unsigned short* w3sw = w2sw + 32768;            // 2048 el
    prep_fb<<<712, 256, 0, stream>>>(W1, W2, W3, w1sw, w2sw, w3sw);
    edge_head_fb<<<7813, 256, 0, stream>>>(h, x, spawn, exist, insx, insa, insc,
                                           b1, g1, be1, b2, g2, be2, b3, mu, gma,
                                           w1sw, w2sw, w3sw, (float*)d_out);
  }
}